// Round 4
// baseline (477.640 us; speedup 1.0000x reference)
//
#include <hip/hip_runtime.h>

// EGNN fused layer via MFMA, M=1024, n=hid=64.
// Round 4: weights in LDS (frees 96 VGPR), register double-buffer prefetch of
// pej/x, a-row staged in LDS. Numerics identical to round 3.

#define MM 1024

typedef _Float16 half8 __attribute__((ext_vector_type(8)));
typedef float f32x4 __attribute__((ext_vector_type(4)));
typedef int int4t __attribute__((ext_vector_type(4)));

__device__ __forceinline__ float fsilu(float v) {
    float e = __expf(-v);
    return v * __builtin_amdgcn_rcpf(1.0f + e);
}

// blocks 0..1023: pe_i(+be1)/pe_j rows (1 node per 64-thread block)
// blocks 1024..1151: pack We2 (fp16 hi/lo) and Wx1 (fp16) into MFMA A-fragment order
__global__ void __launch_bounds__(64) egnn_prepack(
    const float* __restrict__ h, const float* __restrict__ We1,
    const float* __restrict__ be1, const float* __restrict__ We2,
    const float* __restrict__ Wx1,
    float* __restrict__ peib, float* __restrict__ pej,
    _Float16* __restrict__ we2hi, _Float16* __restrict__ we2lo,
    _Float16* __restrict__ wx1h)
{
    const int b = blockIdx.x;
    const int tid = threadIdx.x;
    if (b < 1024) {
        const int i = b;
        const int c = tid;
        __shared__ float hrow[64];
        hrow[c] = h[i * 64 + c];
        __syncthreads();
        float acc1 = be1[c], acc2 = 0.0f;
#pragma unroll 8
        for (int cp = 0; cp < 64; ++cp) {
            const float hv = hrow[cp];
            acc1 = fmaf(hv, We1[cp * 64 + c], acc1);
            acc2 = fmaf(hv, We1[(64 + cp) * 64 + c], acc2);
        }
        peib[i * 64 + c] = acc1;
        pej[i * 64 + c]  = acc2;
    } else {
        const int idx = (b - 1024) * 64 + tid;           // 0..8191
        const int e = idx & 7, l = (idx >> 3) & 63, f = (idx >> 9) & 7;
        const int n = f >> 1, s = f & 1;
        const int outc = 16 * n + (l & 15);              // output row (k or kk)
        const int kc   = 32 * s + ((l >> 4) * 8) + e;    // contraction index
        if (idx < 4096) {
            const float wv = We2[kc * 64 + outc];        // We2^T[k][c]
            const _Float16 hi = (_Float16)wv;
            we2hi[idx] = hi;
            we2lo[idx] = (_Float16)(wv - (float)hi);
        } else {
            wx1h[idx - 4096] = (_Float16)Wx1[kc * 64 + outc];  // Wx1^T[kk][k]
        }
    }
}

__global__ void __launch_bounds__(256, 4) egnn_main(
    const float* __restrict__ x, const float* __restrict__ a,
    const float* __restrict__ h, const float* __restrict__ We1,
    const float* __restrict__ peib, const float* __restrict__ pej,
    const _Float16* __restrict__ we2hi, const _Float16* __restrict__ we2lo,
    const _Float16* __restrict__ wx1h,
    const float* __restrict__ be2,
    const float* __restrict__ bx1, const float* __restrict__ Wx2,
    const float* __restrict__ bx2,
    const float* __restrict__ Wh1, const float* __restrict__ bh1,
    const float* __restrict__ Wh2, const float* __restrict__ bh2,
    float* __restrict__ out)
{
    const int i = blockIdx.x;
    const int tid = threadIdx.x;
    const int w = tid >> 6;        // wave id: owns j-cols [16w,16w+16) of each tile
    const int l = tid & 63;
    const int g = l >> 4;
    const int q15 = l & 15;

    // wLDS: [0,512) = We2 hi, [512,1024) = We2 lo, [1024,1536) = Wx1  (half8 units)
    __shared__ half8 wLDS[1536];
    __shared__ __align__(16) float aL[1024];
    __shared__ __align__(16) float peibL[64], wd2L[64], waL[64], be2L[64], bx1L[64], wx2L[64];
    __shared__ __align__(16) float partialL[256];
    __shared__ float xpartL[4][3];
    __shared__ float miL[64], hrowL[64], hid1L[64];

    // ---- stage weights + a-row + per-block vectors into LDS ----
    for (int idx = tid; idx < 1536; idx += 256) {
        const half8* src = (idx < 512)  ? ((const half8*)we2hi) + idx
                         : (idx < 1024) ? ((const half8*)we2lo) + (idx - 512)
                                        : ((const half8*)wx1h) + (idx - 1024);
        wLDS[idx] = *src;
    }
    ((f32x4*)aL)[tid] = ((const f32x4*)(a + i * MM))[tid];
    if (tid < 64) {
        peibL[tid] = peib[i * 64 + tid];
        wd2L[tid]  = We1[128 * 64 + tid];
        waL[tid]   = We1[129 * 64 + tid];
        be2L[tid]  = be2[tid];
        bx1L[tid]  = bx1[tid];
        wx2L[tid]  = Wx2[tid];
        hrowL[tid] = h[i * 64 + tid];
    }
    __syncthreads();

    const float xi0 = x[i * 3 + 0], xi1 = x[i * 3 + 1], xi2 = x[i * 3 + 2];
    const float bx2v = bx2[0];
    const int sl_lo = q15 + 32 * (g & 1);
    const int sl_hi = sl_lo + 16;
    const bool hiSel = (g >= 2);
    const int jbase = 16 * w + q15;

    float msum[4][4];
#pragma unroll
    for (int n = 0; n < 4; ++n)
#pragma unroll
        for (int r = 0; r < 4; ++r) msum[n][r] = 0.0f;
    float xa0 = 0.0f, xa1 = 0.0f, xa2 = 0.0f;

    // ---- register double-buffer prefetch of pej row + x_j ----
    f32x4 pA[2][2], pB[2][2];
    float xjA[3], xjB[3];

    auto pref = [&](f32x4 (&pj)[2][2], float (&xj)[3], int t) {
        const int jn = t * 64 + jbase;
        const float* __restrict__ pr = pej + jn * 64 + 8 * g;
        pj[0][0] = *(const f32x4*)(pr);
        pj[0][1] = *(const f32x4*)(pr + 4);
        pj[1][0] = *(const f32x4*)(pr + 32);
        pj[1][1] = *(const f32x4*)(pr + 36);
        xj[0] = x[jn * 3 + 0];
        xj[1] = x[jn * 3 + 1];
        xj[2] = x[jn * 3 + 2];
    };

    auto body = [&](const f32x4 (&pj)[2][2], const float (&xj)[3], int t) {
        const int jw = t * 64 + jbase;
        const float d0 = xi0 - xj[0], d1 = xi1 - xj[1], d2v = xi2 - xj[2];
        const float dd = fmaf(d0, d0, fmaf(d1, d1, d2v * d2v));
        const float av = aL[jw];
        const float selfmul = (jw == i) ? 0.0f : 1.0f;

        // ---- build P^T B-fragments: lane holds P[j=q15][c-chunk 8g+32s] ----
        half8 P[2];
#pragma unroll
        for (int s = 0; s < 2; ++s) {
            const f32x4 pe0 = *(const f32x4*)&peibL[32 * s + 8 * g];
            const f32x4 pe1 = *(const f32x4*)&peibL[32 * s + 8 * g + 4];
            const f32x4 wd0 = *(const f32x4*)&wd2L[32 * s + 8 * g];
            const f32x4 wd1 = *(const f32x4*)&wd2L[32 * s + 8 * g + 4];
            const f32x4 wa0 = *(const f32x4*)&waL[32 * s + 8 * g];
            const f32x4 wa1 = *(const f32x4*)&waL[32 * s + 8 * g + 4];
#pragma unroll
            for (int e = 0; e < 8; ++e) {
                const float pjv = (e < 4) ? pj[s][0][e] : pj[s][1][e - 4];
                const float pev = (e < 4) ? pe0[e] : pe1[e - 4];
                const float wdv = (e < 4) ? wd0[e] : wd1[e - 4];
                const float wav = (e < 4) ? wa0[e] : wa1[e - 4];
                float pre = pev + pjv;
                pre = fmaf(dd, wdv, pre);
                pre = fmaf(av, wav, pre);
                P[s][e] = (_Float16)fsilu(pre);     // RTN convert
            }
        }

        // ---- D1 = We2^T @ P^T (+be2), fp16 split hi/lo, weights from LDS ----
        f32x4 acc1[4];
#pragma unroll
        for (int n = 0; n < 4; ++n) acc1[n] = *(const f32x4*)&be2L[16 * n + 4 * g];
#pragma unroll
        for (int n = 0; n < 4; ++n) {
            acc1[n] = __builtin_amdgcn_mfma_f32_16x16x32_f16(wLDS[(n * 2 + 0) * 64 + l], P[0], acc1[n], 0, 0, 0);
            acc1[n] = __builtin_amdgcn_mfma_f32_16x16x32_f16(wLDS[(n * 2 + 1) * 64 + l], P[1], acc1[n], 0, 0, 0);
            acc1[n] = __builtin_amdgcn_mfma_f32_16x16x32_f16(wLDS[512 + (n * 2 + 0) * 64 + l], P[0], acc1[n], 0, 0, 0);
            acc1[n] = __builtin_amdgcn_mfma_f32_16x16x32_f16(wLDS[512 + (n * 2 + 1) * 64 + l], P[1], acc1[n], 0, 0, 0);
        }

        // ---- m = silu(D1); accumulate m_i (f32, self-masked); pack m^T fp16 ----
        float mf[4][4];
        int srcp[4][2];
#pragma unroll
        for (int n = 0; n < 4; ++n) {
#pragma unroll
            for (int r = 0; r < 4; ++r) {
                mf[n][r] = fsilu(acc1[n][r]);
                msum[n][r] = fmaf(mf[n][r], selfmul, msum[n][r]);
            }
            srcp[n][0] = __builtin_bit_cast(int, __builtin_amdgcn_cvt_pkrtz(mf[n][0], mf[n][1]));
            srcp[n][1] = __builtin_bit_cast(int, __builtin_amdgcn_cvt_pkrtz(mf[n][2], mf[n][3]));
        }

        // ---- regroup C-layout rows (4g+r) -> B-layout k-chunks (8g+e) ----
        half8 B2[2];
#pragma unroll
        for (int s2 = 0; s2 < 2; ++s2) {
            int4t bi;
#pragma unroll
            for (int p = 0; p < 4; ++p) {
                const int sl = (p < 2) ? sl_lo : sl_hi;
                const int va = __shfl(srcp[2 * s2][p & 1], sl, 64);
                const int vb = __shfl(srcp[2 * s2 + 1][p & 1], sl, 64);
                bi[p] = hiSel ? vb : va;
            }
            B2[s2] = __builtin_bit_cast(half8, bi);
        }

        // ---- T^T = Wx1^T @ m^T (+bx1), weights from LDS ----
        f32x4 acc2[4];
#pragma unroll
        for (int n = 0; n < 4; ++n) acc2[n] = *(const f32x4*)&bx1L[16 * n + 4 * g];
#pragma unroll
        for (int n = 0; n < 4; ++n) {
            acc2[n] = __builtin_amdgcn_mfma_f32_16x16x32_f16(wLDS[1024 + (n * 2 + 0) * 64 + l], B2[0], acc2[n], 0, 0, 0);
            acc2[n] = __builtin_amdgcn_mfma_f32_16x16x32_f16(wLDS[1024 + (n * 2 + 1) * 64 + l], B2[1], acc2[n], 0, 0, 0);
        }

        // ---- s[j] = bx2 + sum_kk silu(T)*Wx2[kk]; x-update accumulate ----
        float sp = 0.0f;
#pragma unroll
        for (int n = 0; n < 4; ++n) {
            const f32x4 wq = *(const f32x4*)&wx2L[16 * n + 4 * g];
#pragma unroll
            for (int r = 0; r < 4; ++r) sp = fmaf(fsilu(acc2[n][r]), wq[r], sp);
        }
        sp += __shfl_xor(sp, 16, 64);
        sp += __shfl_xor(sp, 32, 64);       // all 4 g-groups now hold full s[j]
        const float sv = sp + bx2v;
        xa0 = fmaf(d0, sv, xa0);            // 4x duplicated across g; 0.25 at end
        xa1 = fmaf(d1, sv, xa1);
        xa2 = fmaf(d2v, sv, xa2);
    };

    pref(pA, xjA, 0);
    for (int t = 0; t < 16; t += 2) {
        pref(pB, xjB, t + 1);
        body(pA, xjA, t);
        if (t + 2 < 16) pref(pA, xjA, t + 2);
        body(pB, xjB, t + 1);
    }

    // ---- m_i: reduce over the 16 j-lanes, write per-wave partials ----
#pragma unroll
    for (int n = 0; n < 4; ++n)
#pragma unroll
        for (int r = 0; r < 4; ++r) {
            float v = msum[n][r];
            v += __shfl_xor(v, 1, 64);
            v += __shfl_xor(v, 2, 64);
            v += __shfl_xor(v, 4, 64);
            v += __shfl_xor(v, 8, 64);
            msum[n][r] = v;
        }
    if (q15 == 0) {
#pragma unroll
        for (int n = 0; n < 4; ++n) {
            f32x4 sv4;
            sv4[0] = msum[n][0]; sv4[1] = msum[n][1];
            sv4[2] = msum[n][2]; sv4[3] = msum[n][3];
            *(f32x4*)&partialL[w * 64 + 16 * n + 4 * g] = sv4;   // k = 16n+4g+r
        }
    }
    {
        float v0 = xa0, v1 = xa1, v2 = xa2;
        for (int sft = 1; sft < 64; sft <<= 1) {
            v0 += __shfl_xor(v0, sft, 64);
            v1 += __shfl_xor(v1, sft, 64);
            v2 += __shfl_xor(v2, sft, 64);
        }
        if (l == 0) { xpartL[w][0] = v0; xpartL[w][1] = v1; xpartL[w][2] = v2; }
    }
    __syncthreads();

    if (tid < 64)
        miL[tid] = partialL[tid] + partialL[64 + tid] + partialL[128 + tid] + partialL[192 + tid];
    __syncthreads();

    // phi_h layer 1
    if (tid < 64) {
        const int kk = tid;
        float a0 = bh1[kk], a1 = 0.0f;
#pragma unroll 8
        for (int c = 0; c < 64; ++c) {
            a0 = fmaf(hrowL[c], Wh1[c * 64 + kk], a0);
            a1 = fmaf(miL[c], Wh1[(64 + c) * 64 + kk], a1);
        }
        hid1L[kk] = fsilu(a0 + a1);
    }
    __syncthreads();

    // phi_h layer 2 -> h_new
    if (tid < 64) {
        float accv = bh2[tid];
#pragma unroll 8
        for (int kk = 0; kk < 64; ++kk) accv = fmaf(hid1L[kk], Wh2[kk * 64 + tid], accv);
        out[3072 + i * 64 + tid] = accv;
    }
    // x_new (0.25 compensates the 4x g-group duplication of xa)
    if (tid == 0) {
        const float C = 0.25f / 1023.0f;
        out[i * 3 + 0] = xi0 + C * (xpartL[0][0] + xpartL[1][0] + xpartL[2][0] + xpartL[3][0]);
        out[i * 3 + 1] = xi1 + C * (xpartL[0][1] + xpartL[1][1] + xpartL[2][1] + xpartL[3][1]);
        out[i * 3 + 2] = xi2 + C * (xpartL[0][2] + xpartL[1][2] + xpartL[2][2] + xpartL[3][2]);
    }
}

extern "C" void kernel_launch(void* const* d_in, const int* in_sizes, int n_in,
                              void* d_out, int out_size, void* d_ws, size_t ws_size,
                              hipStream_t stream) {
    const float* x   = (const float*)d_in[0];
    const float* a   = (const float*)d_in[1];
    const float* h   = (const float*)d_in[2];
    const float* We1 = (const float*)d_in[3];
    const float* be1 = (const float*)d_in[4];
    const float* We2 = (const float*)d_in[5];
    const float* be2 = (const float*)d_in[6];
    const float* Wx1 = (const float*)d_in[7];
    const float* bx1 = (const float*)d_in[8];
    const float* Wx2 = (const float*)d_in[9];
    const float* bx2 = (const float*)d_in[10];
    const float* Wh1 = (const float*)d_in[11];
    const float* bh1 = (const float*)d_in[12];
    const float* Wh2 = (const float*)d_in[13];
    const float* bh2 = (const float*)d_in[14];
    float* out = (float*)d_out;

    float* peib = (float*)d_ws;                    // [1024*64]
    float* pej  = peib + 65536;                    // [1024*64]
    _Float16* we2hi = (_Float16*)(pej + 65536);    // 4096 fp16
    _Float16* we2lo = we2hi + 4096;                // 4096 fp16
    _Float16* wx1h  = we2lo + 4096;                // 4096 fp16

    egnn_prepack<<<dim3(1152), dim3(64), 0, stream>>>(
        h, We1, be1, We2, Wx1, peib, pej, we2hi, we2lo, wx1h);
    egnn_main<<<dim3(1024), dim3(256), 0, stream>>>(
        x, a, h, We1, peib, pej, we2hi, we2lo, wx1h,
        be2, bx1, Wx2, bx2, Wh1, bh1, Wh2, bh2, out);
}

// Round 5
// 203.942 us; speedup vs baseline: 2.3420x; 2.3420x over previous
//
#include <hip/hip_runtime.h>

// EGNN fused layer via MFMA, M=1024, n=hid=64.
// Round 5: round-4 ideas (weights in LDS, a-row in LDS, register double-buffer
// prefetch of pej/x) re-implemented scratch-proof: no lambdas, no by-ref array
// params; named locals + _Pragma("unroll") macros only. Numerics == round 3.

#define MM 1024

typedef _Float16 half8 __attribute__((ext_vector_type(8)));
typedef float f32x4 __attribute__((ext_vector_type(4)));
typedef int int4t __attribute__((ext_vector_type(4)));

__device__ __forceinline__ float fsilu(float v) {
    float e = __expf(-v);
    return v * __builtin_amdgcn_rcpf(1.0f + e);
}

// blocks 0..1023: pe_i(+be1)/pe_j rows (1 node per 64-thread block)
// blocks 1024..1151: pack We2 (fp16 hi/lo) and Wx1 (fp16) into MFMA A-fragment order
__global__ void __launch_bounds__(64) egnn_prepack(
    const float* __restrict__ h, const float* __restrict__ We1,
    const float* __restrict__ be1, const float* __restrict__ We2,
    const float* __restrict__ Wx1,
    float* __restrict__ peib, float* __restrict__ pej,
    _Float16* __restrict__ we2hi, _Float16* __restrict__ we2lo,
    _Float16* __restrict__ wx1h)
{
    const int b = blockIdx.x;
    const int tid = threadIdx.x;
    if (b < 1024) {
        const int i = b;
        const int c = tid;
        __shared__ float hrow[64];
        hrow[c] = h[i * 64 + c];
        __syncthreads();
        float acc1 = be1[c], acc2 = 0.0f;
#pragma unroll 8
        for (int cp = 0; cp < 64; ++cp) {
            const float hv = hrow[cp];
            acc1 = fmaf(hv, We1[cp * 64 + c], acc1);
            acc2 = fmaf(hv, We1[(64 + cp) * 64 + c], acc2);
        }
        peib[i * 64 + c] = acc1;
        pej[i * 64 + c]  = acc2;
    } else {
        const int idx = (b - 1024) * 64 + tid;           // 0..8191
        const int e = idx & 7, l = (idx >> 3) & 63, f = (idx >> 9) & 7;
        const int n = f >> 1, s = f & 1;
        const int outc = 16 * n + (l & 15);              // output row (k or kk)
        const int kc   = 32 * s + ((l >> 4) * 8) + e;    // contraction index
        if (idx < 4096) {
            const float wv = We2[kc * 64 + outc];        // We2^T[k][c]
            const _Float16 hi = (_Float16)wv;
            we2hi[idx] = hi;
            we2lo[idx] = (_Float16)(wv - (float)hi);
        } else {
            wx1h[idx - 4096] = (_Float16)Wx1[kc * 64 + outc];  // Wx1^T[kk][k]
        }
    }
}

// ---- prefetch one tile's pej row chunks + x_j into named registers ----
#define EGNN_PREF(PJ0, PJ1, PJ2, PJ3, XJ0, XJ1, XJ2, TT)                       \
  {                                                                            \
    const int jn_ = (TT) * 64 + jbase;                                         \
    const float* __restrict__ pr_ = pej + jn_ * 64 + 8 * g;                    \
    PJ0 = *(const f32x4*)(pr_);                                                \
    PJ1 = *(const f32x4*)(pr_ + 4);                                            \
    PJ2 = *(const f32x4*)(pr_ + 32);                                           \
    PJ3 = *(const f32x4*)(pr_ + 36);                                           \
    XJ0 = x[jn_ * 3 + 0];                                                      \
    XJ1 = x[jn_ * 3 + 1];                                                      \
    XJ2 = x[jn_ * 3 + 2];                                                      \
  }

// ---- full per-tile body; all locals named, all array idx static post-unroll ----
#define EGNN_BODY(PJ0, PJ1, PJ2, PJ3, XJ0, XJ1, XJ2, TT)                       \
  {                                                                            \
    const int jw_ = (TT) * 64 + jbase;                                         \
    const float d0_ = xi0 - (XJ0), d1_ = xi1 - (XJ1), d2_ = xi2 - (XJ2);       \
    const float dd_ = fmaf(d0_, d0_, fmaf(d1_, d1_, d2_ * d2_));               \
    const float av_ = aL[jw_];                                                 \
    const float sm_ = (jw_ == i) ? 0.0f : 1.0f;                                \
    half8 P0_, P1_;                                                            \
    _Pragma("unroll") for (int s = 0; s < 2; ++s) {                            \
      const f32x4 pjlo_ = s ? (PJ2) : (PJ0);                                   \
      const f32x4 pjhi_ = s ? (PJ3) : (PJ1);                                   \
      const f32x4 pe0_ = *(const f32x4*)&peibL[32 * s + 8 * g];                \
      const f32x4 pe1_ = *(const f32x4*)&peibL[32 * s + 8 * g + 4];            \
      const f32x4 wd0_ = *(const f32x4*)&wd2L[32 * s + 8 * g];                 \
      const f32x4 wd1_ = *(const f32x4*)&wd2L[32 * s + 8 * g + 4];             \
      const f32x4 wa0_ = *(const f32x4*)&waL[32 * s + 8 * g];                  \
      const f32x4 wa1_ = *(const f32x4*)&waL[32 * s + 8 * g + 4];              \
      half8 Pt_;                                                               \
      _Pragma("unroll") for (int e = 0; e < 8; ++e) {                          \
        const float pjv_ = (e < 4) ? pjlo_[e] : pjhi_[e - 4];                  \
        const float pev_ = (e < 4) ? pe0_[e] : pe1_[e - 4];                    \
        const float wdv_ = (e < 4) ? wd0_[e] : wd1_[e - 4];                    \
        const float wav_ = (e < 4) ? wa0_[e] : wa1_[e - 4];                    \
        float pre_ = pev_ + pjv_;                                              \
        pre_ = fmaf(dd_, wdv_, pre_);                                          \
        pre_ = fmaf(av_, wav_, pre_);                                          \
        Pt_[e] = (_Float16)fsilu(pre_);                                        \
      }                                                                        \
      if (s == 0) P0_ = Pt_; else P1_ = Pt_;                                   \
    }                                                                          \
    f32x4 acc1_[4];                                                            \
    _Pragma("unroll") for (int n = 0; n < 4; ++n)                              \
      acc1_[n] = *(const f32x4*)&be2L[16 * n + 4 * g];                         \
    _Pragma("unroll") for (int n = 0; n < 4; ++n) {                            \
      acc1_[n] = __builtin_amdgcn_mfma_f32_16x16x32_f16(wLDS[(n * 2 + 0) * 64 + l], P0_, acc1_[n], 0, 0, 0); \
      acc1_[n] = __builtin_amdgcn_mfma_f32_16x16x32_f16(wLDS[(n * 2 + 1) * 64 + l], P1_, acc1_[n], 0, 0, 0); \
      acc1_[n] = __builtin_amdgcn_mfma_f32_16x16x32_f16(wLDS[512 + (n * 2 + 0) * 64 + l], P0_, acc1_[n], 0, 0, 0); \
      acc1_[n] = __builtin_amdgcn_mfma_f32_16x16x32_f16(wLDS[512 + (n * 2 + 1) * 64 + l], P1_, acc1_[n], 0, 0, 0); \
    }                                                                          \
    int srcp_[4][2];                                                           \
    _Pragma("unroll") for (int n = 0; n < 4; ++n) {                            \
      const float m0_ = fsilu(acc1_[n][0]);                                    \
      const float m1_ = fsilu(acc1_[n][1]);                                    \
      const float m2_ = fsilu(acc1_[n][2]);                                    \
      const float m3_ = fsilu(acc1_[n][3]);                                    \
      msum[n][0] = fmaf(m0_, sm_, msum[n][0]);                                 \
      msum[n][1] = fmaf(m1_, sm_, msum[n][1]);                                 \
      msum[n][2] = fmaf(m2_, sm_, msum[n][2]);                                 \
      msum[n][3] = fmaf(m3_, sm_, msum[n][3]);                                 \
      srcp_[n][0] = __builtin_bit_cast(int, __builtin_amdgcn_cvt_pkrtz(m0_, m1_)); \
      srcp_[n][1] = __builtin_bit_cast(int, __builtin_amdgcn_cvt_pkrtz(m2_, m3_)); \
    }                                                                          \
    half8 B20_, B21_;                                                          \
    _Pragma("unroll") for (int s2 = 0; s2 < 2; ++s2) {                         \
      int4t bi_;                                                               \
      _Pragma("unroll") for (int p = 0; p < 4; ++p) {                          \
        const int sl_ = (p < 2) ? sl_lo : sl_hi;                               \
        const int va_ = __shfl(srcp_[2 * s2][p & 1], sl_, 64);                 \
        const int vb_ = __shfl(srcp_[2 * s2 + 1][p & 1], sl_, 64);             \
        bi_[p] = hiSel ? vb_ : va_;                                            \
      }                                                                        \
      if (s2 == 0) B20_ = __builtin_bit_cast(half8, bi_);                      \
      else B21_ = __builtin_bit_cast(half8, bi_);                              \
    }                                                                          \
    f32x4 acc2_[4];                                                            \
    _Pragma("unroll") for (int n = 0; n < 4; ++n)                              \
      acc2_[n] = *(const f32x4*)&bx1L[16 * n + 4 * g];                         \
    _Pragma("unroll") for (int n = 0; n < 4; ++n) {                            \
      acc2_[n] = __builtin_amdgcn_mfma_f32_16x16x32_f16(wLDS[1024 + (n * 2 + 0) * 64 + l], B20_, acc2_[n], 0, 0, 0); \
      acc2_[n] = __builtin_amdgcn_mfma_f32_16x16x32_f16(wLDS[1024 + (n * 2 + 1) * 64 + l], B21_, acc2_[n], 0, 0, 0); \
    }                                                                          \
    float sp_ = 0.0f;                                                          \
    _Pragma("unroll") for (int n = 0; n < 4; ++n) {                            \
      const f32x4 wq_ = *(const f32x4*)&wx2L[16 * n + 4 * g];                  \
      sp_ = fmaf(fsilu(acc2_[n][0]), wq_[0], sp_);                             \
      sp_ = fmaf(fsilu(acc2_[n][1]), wq_[1], sp_);                             \
      sp_ = fmaf(fsilu(acc2_[n][2]), wq_[2], sp_);                             \
      sp_ = fmaf(fsilu(acc2_[n][3]), wq_[3], sp_);                             \
    }                                                                          \
    sp_ += __shfl_xor(sp_, 16, 64);                                            \
    sp_ += __shfl_xor(sp_, 32, 64);                                            \
    const float sv_ = sp_ + bx2v;                                              \
    xa0 = fmaf(d0_, sv_, xa0);                                                 \
    xa1 = fmaf(d1_, sv_, xa1);                                                 \
    xa2 = fmaf(d2_, sv_, xa2);                                                 \
  }

__global__ void __launch_bounds__(256, 2) egnn_main(
    const float* __restrict__ x, const float* __restrict__ a,
    const float* __restrict__ h, const float* __restrict__ We1,
    const float* __restrict__ peib, const float* __restrict__ pej,
    const _Float16* __restrict__ we2hi, const _Float16* __restrict__ we2lo,
    const _Float16* __restrict__ wx1h,
    const float* __restrict__ be2,
    const float* __restrict__ bx1, const float* __restrict__ Wx2,
    const float* __restrict__ bx2,
    const float* __restrict__ Wh1, const float* __restrict__ bh1,
    const float* __restrict__ Wh2, const float* __restrict__ bh2,
    float* __restrict__ out)
{
    const int i = blockIdx.x;
    const int tid = threadIdx.x;
    const int w = tid >> 6;        // wave id: owns j-cols [16w,16w+16) of each tile
    const int l = tid & 63;
    const int g = l >> 4;
    const int q15 = l & 15;

    // wLDS: [0,512) = We2 hi, [512,1024) = We2 lo, [1024,1536) = Wx1  (half8 units)
    __shared__ half8 wLDS[1536];
    __shared__ __align__(16) float aL[1024];
    __shared__ __align__(16) float peibL[64], wd2L[64], waL[64], be2L[64], bx1L[64], wx2L[64];
    __shared__ __align__(16) float partialL[256];
    __shared__ float xpartL[4][3];
    __shared__ float miL[64], hrowL[64], hid1L[64];

    // ---- stage weights + a-row + per-block vectors into LDS ----
    for (int idx = tid; idx < 1536; idx += 256) {
        const half8* src = (idx < 512)  ? ((const half8*)we2hi) + idx
                         : (idx < 1024) ? ((const half8*)we2lo) + (idx - 512)
                                        : ((const half8*)wx1h) + (idx - 1024);
        wLDS[idx] = *src;
    }
    ((f32x4*)aL)[tid] = ((const f32x4*)(a + i * MM))[tid];
    if (tid < 64) {
        peibL[tid] = peib[i * 64 + tid];
        wd2L[tid]  = We1[128 * 64 + tid];
        waL[tid]   = We1[129 * 64 + tid];
        be2L[tid]  = be2[tid];
        bx1L[tid]  = bx1[tid];
        wx2L[tid]  = Wx2[tid];
        hrowL[tid] = h[i * 64 + tid];
    }
    __syncthreads();

    const float xi0 = x[i * 3 + 0], xi1 = x[i * 3 + 1], xi2 = x[i * 3 + 2];
    const float bx2v = bx2[0];
    const int sl_lo = q15 + 32 * (g & 1);
    const int sl_hi = sl_lo + 16;
    const bool hiSel = (g >= 2);
    const int jbase = 16 * w + q15;

    float msum[4][4];
#pragma unroll
    for (int n = 0; n < 4; ++n)
#pragma unroll
        for (int r = 0; r < 4; ++r) msum[n][r] = 0.0f;
    float xa0 = 0.0f, xa1 = 0.0f, xa2 = 0.0f;

    // ---- register double-buffer: named locals only (no arrays, no lambdas) ----
    f32x4 pjA0, pjA1, pjA2, pjA3;
    f32x4 pjB0, pjB1, pjB2, pjB3;
    float xjA0, xjA1, xjA2, xjB0, xjB1, xjB2;

    EGNN_PREF(pjA0, pjA1, pjA2, pjA3, xjA0, xjA1, xjA2, 0)
    for (int t = 0; t < 16; t += 2) {
        EGNN_PREF(pjB0, pjB1, pjB2, pjB3, xjB0, xjB1, xjB2, t + 1)
        EGNN_BODY(pjA0, pjA1, pjA2, pjA3, xjA0, xjA1, xjA2, t)
        if (t + 2 < 16)
            EGNN_PREF(pjA0, pjA1, pjA2, pjA3, xjA0, xjA1, xjA2, t + 2)
        EGNN_BODY(pjB0, pjB1, pjB2, pjB3, xjB0, xjB1, xjB2, t + 1)
    }

    // ---- m_i: reduce over the 16 j-lanes, write per-wave partials ----
#pragma unroll
    for (int n = 0; n < 4; ++n)
#pragma unroll
        for (int r = 0; r < 4; ++r) {
            float v = msum[n][r];
            v += __shfl_xor(v, 1, 64);
            v += __shfl_xor(v, 2, 64);
            v += __shfl_xor(v, 4, 64);
            v += __shfl_xor(v, 8, 64);
            msum[n][r] = v;
        }
    if (q15 == 0) {
#pragma unroll
        for (int n = 0; n < 4; ++n) {
            f32x4 sv4;
            sv4[0] = msum[n][0]; sv4[1] = msum[n][1];
            sv4[2] = msum[n][2]; sv4[3] = msum[n][3];
            *(f32x4*)&partialL[w * 64 + 16 * n + 4 * g] = sv4;   // k = 16n+4g+r
        }
    }
    {
        float v0 = xa0, v1 = xa1, v2 = xa2;
        for (int sft = 1; sft < 64; sft <<= 1) {
            v0 += __shfl_xor(v0, sft, 64);
            v1 += __shfl_xor(v1, sft, 64);
            v2 += __shfl_xor(v2, sft, 64);
        }
        if (l == 0) { xpartL[w][0] = v0; xpartL[w][1] = v1; xpartL[w][2] = v2; }
    }
    __syncthreads();

    if (tid < 64)
        miL[tid] = partialL[tid] + partialL[64 + tid] + partialL[128 + tid] + partialL[192 + tid];
    __syncthreads();

    // phi_h layer 1
    if (tid < 64) {
        const int kk = tid;
        float a0 = bh1[kk], a1 = 0.0f;
#pragma unroll 8
        for (int c = 0; c < 64; ++c) {
            a0 = fmaf(hrowL[c], Wh1[c * 64 + kk], a0);
            a1 = fmaf(miL[c], Wh1[(64 + c) * 64 + kk], a1);
        }
        hid1L[kk] = fsilu(a0 + a1);
    }
    __syncthreads();

    // phi_h layer 2 -> h_new
    if (tid < 64) {
        float accv = bh2[tid];
#pragma unroll 8
        for (int kk = 0; kk < 64; ++kk) accv = fmaf(hid1L[kk], Wh2[kk * 64 + tid], accv);
        out[3072 + i * 64 + tid] = accv;
    }
    // x_new (0.25 compensates the 4x g-group duplication of xa)
    if (tid == 0) {
        const float C = 0.25f / 1023.0f;
        out[i * 3 + 0] = xi0 + C * (xpartL[0][0] + xpartL[1][0] + xpartL[2][0] + xpartL[3][0]);
        out[i * 3 + 1] = xi1 + C * (xpartL[0][1] + xpartL[1][1] + xpartL[2][1] + xpartL[3][1]);
        out[i * 3 + 2] = xi2 + C * (xpartL[0][2] + xpartL[1][2] + xpartL[2][2] + xpartL[3][2]);
    }
}

extern "C" void kernel_launch(void* const* d_in, const int* in_sizes, int n_in,
                              void* d_out, int out_size, void* d_ws, size_t ws_size,
                              hipStream_t stream) {
    const float* x   = (const float*)d_in[0];
    const float* a   = (const float*)d_in[1];
    const float* h   = (const float*)d_in[2];
    const float* We1 = (const float*)d_in[3];
    const float* be1 = (const float*)d_in[4];
    const float* We2 = (const float*)d_in[5];
    const float* be2 = (const float*)d_in[6];
    const float* Wx1 = (const float*)d_in[7];
    const float* bx1 = (const float*)d_in[8];
    const float* Wx2 = (const float*)d_in[9];
    const float* bx2 = (const float*)d_in[10];
    const float* Wh1 = (const float*)d_in[11];
    const float* bh1 = (const float*)d_in[12];
    const float* Wh2 = (const float*)d_in[13];
    const float* bh2 = (const float*)d_in[14];
    float* out = (float*)d_out;

    float* peib = (float*)d_ws;                    // [1024*64]
    float* pej  = peib + 65536;                    // [1024*64]
    _Float16* we2hi = (_Float16*)(pej + 65536);    // 4096 fp16
    _Float16* we2lo = we2hi + 4096;                // 4096 fp16
    _Float16* wx1h  = we2lo + 4096;                // 4096 fp16

    egnn_prepack<<<dim3(1152), dim3(64), 0, stream>>>(
        h, We1, be1, We2, Wx1, peib, pej, we2hi, we2lo, wx1h);
    egnn_main<<<dim3(1024), dim3(256), 0, stream>>>(
        x, a, h, We1, peib, pej, we2hi, we2lo, wx1h,
        be2, bx1, Wx2, bx2, Wh1, bh1, Wh2, bh2, out);
}